// Round 3
// baseline (707.708 us; speedup 1.0000x reference)
//
#include <hip/hip_runtime.h>

#define NB 8
#define NC 512
#define NL 8192
#define NH 8
#define ND 64

typedef float f32x4 __attribute__((ext_vector_type(4)));
typedef __bf16 bf16x8 __attribute__((ext_vector_type(8)));
typedef unsigned int u32x4 __attribute__((ext_vector_type(4)));

__device__ __forceinline__ unsigned short f2bf(float f) {
    unsigned u = __builtin_bit_cast(unsigned, f);
    u += 0x7fffu + ((u >> 16) & 1u);
    return (unsigned short)(u >> 16);
}
__device__ __forceinline__ bf16x8 frag_from_u32x4(u32x4 v) {
    return __builtin_bit_cast(bf16x8, v);
}
// LDS fragment load with only-4B-aligned rows -> dword reads (fold kernel only)
__device__ __forceinline__ bf16x8 ld_frag_lds(const unsigned short* p) {
    const unsigned* q = (const unsigned*)p;
    u32x4 v = { q[0], q[1], q[2], q[3] };
    return frag_from_u32x4(v);
}
// Global fragment load: 16B aligned
__device__ __forceinline__ bf16x8 ld_frag_g16(const unsigned short* p) {
    return frag_from_u32x4(*(const u32x4*)p);
}

// async global->LDS, 16B per lane. dest = wave-uniform base + lane*16 (m104).
__device__ __forceinline__ void gload16(const unsigned short* g, unsigned short* l) {
    __builtin_amdgcn_global_load_lds(
        (const __attribute__((address_space(1))) unsigned int*)g,
        (__attribute__((address_space(3))) unsigned int*)l, 16, 0, 0);
}

// One-launch prep: W converts (Wk,Wv,Wq,Wr -> contiguous bf16), bias concat, zero ctx+rowsum.
// grid covers 4*WN + 2*NC + NZERO elements exactly.
__global__ __launch_bounds__(256) void prep_kernel(
    const float* __restrict__ Wk, const float* __restrict__ Wv,
    const float* __restrict__ Wq, const float* __restrict__ Wr,
    const float* __restrict__ bk, const float* __restrict__ bv,
    unsigned short* __restrict__ Wb,  // [4*WN] bf16: Wk|Wv|Wq|Wr
    float* __restrict__ bkv,          // [2*NC]
    float* __restrict__ zf)           // ctxb + rowsum region
{
    const int WN = NC * NC;
    int i = blockIdx.x * 256 + threadIdx.x;
    if (i < 4 * WN) {
        const float* src = (i < WN) ? Wk : (i < 2 * WN) ? Wv : (i < 3 * WN) ? Wq : Wr;
        Wb[i] = f2bf(src[i & (WN - 1)]);
    } else if (i < 4 * WN + 2 * NC) {
        int j = i - 4 * WN;
        bkv[j] = (j < NC) ? bk[j] : bv[j - NC];
    } else {
        zf[i - (4 * WN + 2 * NC)] = 0.f;
    }
}

// fp32 [b][c][l] -> bf16 [b][l][c]. 64x64 tiles through LDS. Two sources in one launch
// (grid.z = 2*NB: z<NB -> X0->Y0, else X1->Y1).
__device__ __forceinline__ int ltidx(int c, int l) {
    return c * 64 + ((((l) >> 2) ^ ((c >> 2) & 15)) << 2) + (l & 3);
}
__global__ __launch_bounds__(256) void transpose_cvt_kernel(
    const float* __restrict__ X0, const float* __restrict__ X1,
    unsigned short* __restrict__ Y0, unsigned short* __restrict__ Y1)
{
    const int bz = blockIdx.z;
    const float* X = (bz < NB) ? X0 : X1;
    unsigned short* Y = (bz < NB) ? Y0 : Y1;
    const int b = bz & (NB - 1);
    const int l0 = blockIdx.x * 64, c0 = blockIdx.y * 64;
    const int t = threadIdx.x;
    __shared__ alignas(16) unsigned short lt[64 * 64];
    const float* Xb = X + (size_t)b * NC * NL;
    #pragma unroll
    for (int it = 0; it < 4; ++it) {
        const int c = it * 16 + (t >> 4), l4 = (t & 15) * 4;
        f32x4 v = *(const f32x4*)(Xb + (size_t)(c0 + c) * NL + l0 + l4);
        unsigned lo = f2bf(v.x) | ((unsigned)f2bf(v.y) << 16);
        unsigned hi = f2bf(v.z) | ((unsigned)f2bf(v.w) << 16);
        unsigned* p = (unsigned*)&lt[ltidx(c, l4)];
        p[0] = lo; p[1] = hi;
    }
    __syncthreads();
    unsigned short* Yb = Y + (size_t)b * NL * NC;
    #pragma unroll
    for (int it = 0; it < 2; ++it) {
        const int l = it * 32 + (t >> 3), c8 = (t & 7) * 8;
        u32x4 o;
        #pragma unroll
        for (int d = 0; d < 4; ++d) {
            unsigned lo = lt[ltidx(c8 + 2 * d, l)];
            unsigned hi = lt[ltidx(c8 + 2 * d + 1, l)];
            o[d] = lo | (hi << 16);
        }
        *(u32x4*)(Yb + (size_t)(l0 + l) * NC + c0 + c8) = o;
    }
}

// Y[b,o,l] = sum_c W[o,c] Xt[b,l,c] + bias[o]
// m97 structure, BK=64 (8 K-steps, half the barriers of BK=32):
//   global_load_lds(16B) into linear LDS [128 rows][8 chunks], phys chunk = q ^ (r&7)
//   (row stride 128B is bank-invariant; XOR spreads 16 lanes 2-way = free),
//   ds_read_b128 fragments, 32 MFMA / wave / K-step.
// Epilogues: EXPK (KV: rows<NC get exp() + rowsum atomics), QSMT (fused per-head
// softmax + transposed bf16 out), RESID (fp32 + resid out).
// grid: (64*MT, NB), XCD-aware swizzle (same nt => same XCD => shared L2 X panel).
template<int MT, bool RESID, bool PERB, bool QSMT, bool EXPK>
__global__ __launch_bounds__(256) void gemm_kernel(
    const unsigned short* __restrict__ Wb,   // [OC][512] bf16 (PERB: [B][512][512])
    const unsigned short* __restrict__ Xt,   // [B][L][512] bf16
    const float* __restrict__ bias,          // [OC]
    const float* __restrict__ resid,         // [B,512,L] float (RESID only)
    void* __restrict__ Yv,                   // bf16 or float
    float* __restrict__ rowsum)              // [B][NC] (EXPK only)
{
    const int bx = blockIdx.x;
    const int g  = bx >> 3;
    const int mt = g % MT;
    const int nt = (g / MT) * 8 + (bx & 7);
    const int b  = blockIdx.y;
    const int t  = threadIdx.x;
    const int wave = t >> 6, lane = t & 63;
    const int m0 = mt * 128, n0 = nt * 128;
    const int wm = (wave & 1) * 64, wn = (wave >> 1) * 64;
    const int OC = MT * 128;

    __shared__ alignas(16) unsigned short lA[128 * 64];
    __shared__ alignas(16) unsigned short lX[128 * 64];

    f32x4 acc[4][4] = {};

    const unsigned short* Wp = Wb + (PERB ? (size_t)b * NC * NC : 0);
    const unsigned short* Xb = Xt + (size_t)b * NL * NC;

    const int lr = lane & 15, q = lane >> 4;
    const unsigned abase = (unsigned)((wm + lr) * 128);
    const unsigned bbase = (unsigned)((wn + lr) * 128);
    const unsigned sw = (unsigned)(lr & 7);

    for (int k0 = 0; k0 < NC; k0 += 64) {
        #pragma unroll
        for (int cc = 0; cc < 4; ++cc) {
            const int pb = wave * 256 + cc * 64;   // wave-uniform LDS chunk base
            const int p  = pb + lane;
            const int r  = p >> 3;
            const int qq = (p & 7) ^ (r & 7);
            gload16(Wp + (size_t)(m0 + r) * NC + k0 + qq * 8, &lA[pb * 8]);
            gload16(Xb + (size_t)(n0 + r) * NC + k0 + qq * 8, &lX[pb * 8]);
        }
        __syncthreads();

        #pragma unroll
        for (int kk = 0; kk < 2; ++kk) {
            const unsigned cq = (((unsigned)(kk * 4 + q)) ^ sw) * 16;
            bf16x8 af[4], bfx[4];
            #pragma unroll
            for (int i = 0; i < 4; ++i)
                af[i] = frag_from_u32x4(*(const u32x4*)((const char*)lA + abase + i * 2048 + cq));
            #pragma unroll
            for (int j = 0; j < 4; ++j)
                bfx[j] = frag_from_u32x4(*(const u32x4*)((const char*)lX + bbase + j * 2048 + cq));
            #pragma unroll
            for (int i = 0; i < 4; ++i)
                #pragma unroll
                for (int j = 0; j < 4; ++j)
                    acc[i][j] = __builtin_amdgcn_mfma_f32_16x16x32_bf16(af[i], bfx[j], acc[i][j], 0, 0, 0);
        }
        __syncthreads();
    }

    // epilogue: C/D layout col=lane&15, row=(lane>>4)*4+reg
    const int col = lane & 15, row0 = (lane >> 4) * 4;

    if constexpr (QSMT) {
        // fused per-head softmax over 64 output channels (= wave's 64 rows),
        // then TRANSPOSED bf16 write Y[b][l][o] (8B packed stores).
        #pragma unroll
        for (int i = 0; i < 4; ++i)
            #pragma unroll
            for (int r = 0; r < 4; ++r) {
                const float bo = bias[m0 + wm + i * 16 + row0 + r];
                #pragma unroll
                for (int j = 0; j < 4; ++j) acc[i][j][r] += bo;
            }
        float inv[4];
        #pragma unroll
        for (int j = 0; j < 4; ++j) {
            float m = -1e30f;
            #pragma unroll
            for (int i = 0; i < 4; ++i)
                #pragma unroll
                for (int r = 0; r < 4; ++r) m = fmaxf(m, acc[i][j][r]);
            m = fmaxf(m, __shfl_xor(m, 16));
            m = fmaxf(m, __shfl_xor(m, 32));
            float s = 0.f;
            #pragma unroll
            for (int i = 0; i < 4; ++i)
                #pragma unroll
                for (int r = 0; r < 4; ++r) {
                    const float e = __expf(acc[i][j][r] - m);
                    acc[i][j][r] = e;
                    s += e;
                }
            s += __shfl_xor(s, 16);
            s += __shfl_xor(s, 32);
            inv[j] = 1.0f / s;
        }
        unsigned short* Yq = (unsigned short*)Yv;
        #pragma unroll
        for (int j = 0; j < 4; ++j) {
            const size_t rowb = (size_t)b * NL * NC + (size_t)(n0 + wn + j * 16 + col) * NC;
            #pragma unroll
            for (int i = 0; i < 4; ++i) {
                const int o0 = m0 + wm + i * 16 + row0;
                unsigned lo = f2bf(acc[i][j][0] * inv[j]) | ((unsigned)f2bf(acc[i][j][1] * inv[j]) << 16);
                unsigned hi = f2bf(acc[i][j][2] * inv[j]) | ((unsigned)f2bf(acc[i][j][3] * inv[j]) << 16);
                *(unsigned long long*)(Yq + rowb + o0) =
                    (unsigned long long)lo | ((unsigned long long)hi << 32);
            }
        }
    } else if constexpr (EXPK) {
        unsigned short* Y = (unsigned short*)Yv;
        if (m0 < NC) {
            // K rows: write UNNORMALIZED exp(val+bias); accumulate per-row sums.
            // softmax normalization deferred to fold_kernel (exp(k)/S == exp(k-m)/S').
            #pragma unroll
            for (int i = 0; i < 4; ++i)
                #pragma unroll
                for (int r = 0; r < 4; ++r) {
                    const int o = m0 + wm + i * 16 + row0 + r;
                    const float bo = bias[o];
                    const size_t rb = (size_t)b * OC * NL + (size_t)o * NL + n0 + wn;
                    float ps = 0.f;
                    #pragma unroll
                    for (int j = 0; j < 4; ++j) {
                        const float e = __expf(acc[i][j][r] + bo);
                        ps += e;
                        Y[rb + j * 16 + col] = f2bf(e);
                    }
                    // reduce over the 16 lanes holding this row (64 cols)
                    #pragma unroll
                    for (int off = 1; off < 16; off <<= 1) ps += __shfl_xor(ps, off);
                    if (col == 0) atomicAdd(&rowsum[(size_t)b * NC + o], ps);
                }
        } else {
            // V rows: plain bias + bf16
            #pragma unroll
            for (int i = 0; i < 4; ++i)
                #pragma unroll
                for (int r = 0; r < 4; ++r) {
                    const int o = m0 + wm + i * 16 + row0 + r;
                    const float bo = bias[o];
                    const size_t rb = (size_t)b * OC * NL + (size_t)o * NL + n0 + wn;
                    #pragma unroll
                    for (int j = 0; j < 4; ++j)
                        Y[rb + j * 16 + col] = f2bf(acc[i][j][r] + bo);
                }
        }
    } else {
        #pragma unroll
        for (int i = 0; i < 4; ++i) {
            #pragma unroll
            for (int r = 0; r < 4; ++r) {
                const int o = m0 + wm + i * 16 + row0 + r;
                const float bo = bias[o];
                const size_t rb = (size_t)b * OC * NL + (size_t)o * NL + n0 + wn;
                if constexpr (RESID) {
                    float* Y = (float*)Yv;
                    #pragma unroll
                    for (int j = 0; j < 4; ++j) {
                        const size_t idx = rb + j * 16 + col;
                        Y[idx] = acc[i][j][r] + bo + resid[idx];
                    }
                } else {
                    unsigned short* Y = (unsigned short*)Yv;
                    #pragma unroll
                    for (int j = 0; j < 4; ++j)
                        Y[rb + j * 16 + col] = f2bf(acc[i][j][r] + bo);
                }
            }
        }
    }
}

// ctx[bh,k,v] = sum_l expK[b,h,k,l] * V[b,h,v,l]   grid (64, 16 L-splits), atomicAdd
__global__ __launch_bounds__(256) void ctx_kernel(
    const unsigned short* __restrict__ KV,   // [B][1024][L]: rows 0-511 exp(K), 512-1023 V
    float* __restrict__ ctx)                 // [64][64][64]
{
    const int bh = blockIdx.x;
    const int sp = blockIdx.y;
    const int t = threadIdx.x;
    const int wave = t >> 6, lane = t & 63;
    const int b = bh >> 3, h = bh & 7;
    const size_t base_k = ((size_t)b * 2 * NC + h * ND) * NL;
    const size_t base_v = base_k + (size_t)NC * NL;
    const int i = wave * 16 + (lane & 15);
    const int koff = (lane >> 4) * 8;
    const unsigned short* Ka = KV + base_k + (size_t)i * NL + koff;

    f32x4 acc[4] = {};
    const int l0 = sp * (NL / 16);
    for (int l = l0; l < l0 + (NL / 16); l += 32) {
        bf16x8 a = ld_frag_g16(Ka + l);
        #pragma unroll
        for (int j = 0; j < 4; ++j) {
            bf16x8 bv = ld_frag_g16(KV + base_v + (size_t)(j * 16 + (lane & 15)) * NL + l + koff);
            acc[j] = __builtin_amdgcn_mfma_f32_16x16x32_bf16(a, bv, acc[j], 0, 0, 0);
        }
    }
    const int col = lane & 15, row0 = (lane >> 4) * 4;
    #pragma unroll
    for (int j = 0; j < 4; ++j)
        #pragma unroll
        for (int r = 0; r < 4; ++r)
            atomicAdd(&ctx[(size_t)bh * (ND * ND) + (size_t)(wave * 16 + row0 + r) * ND + j * 16 + col],
                      acc[j][r]);
}

// M_b[o, h*64+k] = sum_v Wr[o, h*64+v] * (ctx[b,h,k,v] / rowsum[b,h*64+k])
// grid 64 blocks (bh), 512 threads = 8 waves; wave covers 64 o-rows
__global__ __launch_bounds__(512) void fold_kernel(
    const unsigned short* __restrict__ Wrb,  // [512][512] bf16
    const float* __restrict__ ctxb,          // [64][64][64]
    const float* __restrict__ rowsum,        // [B][512]
    unsigned short* __restrict__ Mb)         // [B][512][512] bf16
{
    const int bh = blockIdx.x;
    const int b = bh >> 3, h = bh & 7;
    const int t = threadIdx.x;
    const int wave = t >> 6, lane = t & 63;

    __shared__ unsigned short lc[64 * 66];   // ctx bf16 [k][v], padded stride 66
    const float* cs = ctxb + (size_t)bh * (ND * ND);
    const float* rs = rowsum + (size_t)b * NC + h * ND;
    #pragma unroll
    for (int it = 0; it < 8; ++it) {
        int i = it * 512 + t;
        lc[(i >> 6) * 66 + (i & 63)] = f2bf(cs[i] / rs[i >> 6]);
    }
    __syncthreads();

    const int koff = (lane >> 4) * 8;
    f32x4 acc[4][4] = {};
    #pragma unroll
    for (int kk = 0; kk < 64; kk += 32) {
        bf16x8 af[4], bfx[4];
        #pragma unroll
        for (int i = 0; i < 4; ++i)
            af[i] = ld_frag_g16(Wrb + (size_t)(wave * 64 + i * 16 + (lane & 15)) * NC
                                + h * ND + kk + koff);
        #pragma unroll
        for (int j = 0; j < 4; ++j)
            bfx[j] = ld_frag_lds(&lc[(j * 16 + (lane & 15)) * 66 + kk + koff]);
        #pragma unroll
        for (int i = 0; i < 4; ++i)
            #pragma unroll
            for (int j = 0; j < 4; ++j)
                acc[i][j] = __builtin_amdgcn_mfma_f32_16x16x32_bf16(af[i], bfx[j], acc[i][j], 0, 0, 0);
    }

    const int col = lane & 15, row0 = (lane >> 4) * 4;
    #pragma unroll
    for (int i = 0; i < 4; ++i)
        #pragma unroll
        for (int r = 0; r < 4; ++r) {
            const int o = wave * 64 + i * 16 + row0 + r;
            #pragma unroll
            for (int j = 0; j < 4; ++j)
                Mb[(size_t)b * NC * NC + (size_t)o * NC + h * ND + j * 16 + col]
                    = f2bf(acc[i][j][r]);
        }
}

extern "C" void kernel_launch(void* const* d_in, const int* in_sizes, int n_in,
                              void* d_out, int out_size, void* d_ws, size_t ws_size,
                              hipStream_t stream) {
    (void)in_sizes; (void)n_in; (void)out_size; (void)ws_size;
    const float* input_   = (const float*)d_in[0];
    const float* context_ = (const float*)d_in[1];
    const float* Wk = (const float*)d_in[2];
    const float* bk = (const float*)d_in[3];
    const float* Wq = (const float*)d_in[4];
    const float* bq = (const float*)d_in[5];
    const float* Wv = (const float*)d_in[6];
    const float* bv = (const float*)d_in[7];
    const float* Wr = (const float*)d_in[8];
    const float* br = (const float*)d_in[9];
    float* out = (float*)d_out;

    // workspace layout (~204 MB):
    char* ws = (char*)d_ws;
    unsigned short* Wkvb = (unsigned short*)ws;                     // [1024][512] bf16 = 1 MB
    unsigned short* Wqb  = Wkvb + 2 * NC * NC;                      // 512 KB
    unsigned short* Wrb  = Wqb + NC * NC;                           // 512 KB
    float* bkv  = (float*)(Wrb + NC * NC);                          // 4 KB
    float* ctxb = bkv + 2 * NC;                                     // 1 MB
    float* rowsum = ctxb + NB * NH * ND * ND;                       // 16 KB
    unsigned short* KVp = (unsigned short*)(rowsum + NB * NC);      // [B][1024][L] = 134 MB
    unsigned short* R2  = KVp + (size_t)NB * 2 * NC * NL;           // 67 MB: Xt_ctx, then Qp
    unsigned short* Mb  = KVp;                                      // reuse KVp after ctx/fold
    unsigned short* Xt_in = (unsigned short*)d_out;                 // scratch in out buffer (67 MB)

    // prep: weights->bf16, bias concat, zero ctx+rowsum. 1315840 elems = 5140*256.
    const int WN = NC * NC;
    const int prep_elems = 4 * WN + 2 * NC + (NB * NH * ND * ND + NB * NC);
    prep_kernel<<<(prep_elems + 255) / 256, 256, 0, stream>>>(
        Wk, Wv, Wq, Wr, bk, bv, Wkvb, bkv, ctxb);

    // pre-transpose both inputs to bf16 [b][l][c] (one launch)
    transpose_cvt_kernel<<<dim3(NL / 64, NC / 64, 2 * NB), 256, 0, stream>>>(
        context_, input_, R2, Xt_in);

    // K+V fused projection: [Wk;Wv] (1024x512) @ context -> KVp
    // K rows get exp() + deferred-softmax rowsum
    gemm_kernel<8, false, false, false, true><<<dim3(64 * 8, NB), 256, 0, stream>>>(
        Wkvb, R2, bkv, nullptr, KVp, rowsum);

    // Q projection + fused per-head softmax, TRANSPOSED output Qp[b][l][c] -> R2
    gemm_kernel<4, false, false, true, false><<<dim3(64 * 4, NB), 256, 0, stream>>>(
        Wqb, Xt_in, bq, nullptr, R2, nullptr);

    ctx_kernel<<<dim3(NB * NH, 16), 256, 0, stream>>>(KVp, ctxb);
    fold_kernel<<<NB * NH, 512, 0, stream>>>(Wrb, ctxb, rowsum, Mb);

    // out = M_b @ Qp^T + br + input   (X = Qp[b][l][c], W = Mb per-batch)
    gemm_kernel<4, true, true, false, false><<<dim3(64 * 4, NB), 256, 0, stream>>>(
        Mb, R2, br, input_, out, nullptr);
}

// Round 4
// 675.050 us; speedup vs baseline: 1.0484x; 1.0484x over previous
//
#include <hip/hip_runtime.h>

#define NB 8
#define NC 512
#define NL 8192
#define NH 8
#define ND 64

typedef float f32x4 __attribute__((ext_vector_type(4)));
typedef __bf16 bf16x8 __attribute__((ext_vector_type(8)));
typedef unsigned int u32x4 __attribute__((ext_vector_type(4)));

__device__ __forceinline__ unsigned short f2bf(float f) {
    unsigned u = __builtin_bit_cast(unsigned, f);
    u += 0x7fffu + ((u >> 16) & 1u);
    return (unsigned short)(u >> 16);
}
__device__ __forceinline__ bf16x8 frag_from_u32x4(u32x4 v) {
    return __builtin_bit_cast(bf16x8, v);
}
// LDS fragment load with only-4B-aligned rows -> dword reads (fold kernel only)
__device__ __forceinline__ bf16x8 ld_frag_lds(const unsigned short* p) {
    const unsigned* q = (const unsigned*)p;
    u32x4 v = { q[0], q[1], q[2], q[3] };
    return frag_from_u32x4(v);
}
// Global fragment load: 16B aligned
__device__ __forceinline__ bf16x8 ld_frag_g16(const unsigned short* p) {
    return frag_from_u32x4(*(const u32x4*)p);
}

// async global->LDS, 16B per lane. dest = wave-uniform base + lane*16 (m104).
__device__ __forceinline__ void gload16(const unsigned short* g, unsigned short* l) {
    __builtin_amdgcn_global_load_lds(
        (const __attribute__((address_space(1))) unsigned int*)g,
        (__attribute__((address_space(3))) unsigned int*)l, 16, 0, 0);
}

// prep work item: W converts (Wk,Wv,Wq,Wr -> contiguous bf16), bias concat, zero ctx+rowsum
__device__ __forceinline__ void prep_body(int i,
    const float* __restrict__ Wk, const float* __restrict__ Wv,
    const float* __restrict__ Wq, const float* __restrict__ Wr,
    const float* __restrict__ bk, const float* __restrict__ bv,
    unsigned short* __restrict__ Wb, float* __restrict__ bkv, float* __restrict__ zf)
{
    const int WN = NC * NC;
    if (i < 4 * WN) {
        const float* src = (i < WN) ? Wk : (i < 2 * WN) ? Wv : (i < 3 * WN) ? Wq : Wr;
        Wb[i] = f2bf(src[i & (WN - 1)]);
    } else if (i < 4 * WN + 2 * NC) {
        int j = i - 4 * WN;
        bkv[j] = (j < NC) ? bk[j] : bv[j - NC];
    } else {
        zf[i - (4 * WN + 2 * NC)] = 0.f;
    }
}

// fp32 [b][c][l] -> bf16 [b][l][c], 64x64 tiles through LDS; PLUS fused prep section.
// grid.z = 2*NB+1: z<NB -> X0->Y0, z<2NB -> X1->Y1, z==2NB -> grid-strided prep.
__device__ __forceinline__ int ltidx(int c, int l) {
    return c * 64 + ((((l) >> 2) ^ ((c >> 2) & 15)) << 2) + (l & 3);
}
__global__ __launch_bounds__(256) void transpose_prep_kernel(
    const float* __restrict__ X0, const float* __restrict__ X1,
    unsigned short* __restrict__ Y0, unsigned short* __restrict__ Y1,
    const float* __restrict__ Wk, const float* __restrict__ Wv,
    const float* __restrict__ Wq, const float* __restrict__ Wr,
    const float* __restrict__ bk, const float* __restrict__ bv,
    unsigned short* __restrict__ Wb, float* __restrict__ bkv, float* __restrict__ zf)
{
    const int bz = blockIdx.z;
    const int t = threadIdx.x;
    if (bz == 2 * NB) {
        constexpr int total = 4 * NC * NC + 2 * NC + (NB * NH * ND * ND + NB * NC);
        const int stride = (NL / 64) * (NC / 64) * 256;
        for (int i = (blockIdx.y * (NL / 64) + blockIdx.x) * 256 + t; i < total; i += stride)
            prep_body(i, Wk, Wv, Wq, Wr, bk, bv, Wb, bkv, zf);
        return;
    }
    const float* X = (bz < NB) ? X0 : X1;
    unsigned short* Y = (bz < NB) ? Y0 : Y1;
    const int b = bz & (NB - 1);
    const int l0 = blockIdx.x * 64, c0 = blockIdx.y * 64;
    __shared__ alignas(16) unsigned short lt[64 * 64];
    const float* Xb = X + (size_t)b * NC * NL;
    #pragma unroll
    for (int it = 0; it < 4; ++it) {
        const int c = it * 16 + (t >> 4), l4 = (t & 15) * 4;
        f32x4 v = *(const f32x4*)(Xb + (size_t)(c0 + c) * NL + l0 + l4);
        unsigned lo = f2bf(v.x) | ((unsigned)f2bf(v.y) << 16);
        unsigned hi = f2bf(v.z) | ((unsigned)f2bf(v.w) << 16);
        unsigned* p = (unsigned*)&lt[ltidx(c, l4)];
        p[0] = lo; p[1] = hi;
    }
    __syncthreads();
    unsigned short* Yb = Y + (size_t)b * NL * NC;
    #pragma unroll
    for (int it = 0; it < 2; ++it) {
        const int l = it * 32 + (t >> 3), c8 = (t & 7) * 8;
        u32x4 o;
        #pragma unroll
        for (int d = 0; d < 4; ++d) {
            unsigned lo = lt[ltidx(c8 + 2 * d, l)];
            unsigned hi = lt[ltidx(c8 + 2 * d + 1, l)];
            o[d] = lo | (hi << 16);
        }
        *(u32x4*)(Yb + (size_t)(l0 + l) * NC + c0 + c8) = o;
    }
}

// Y[b,o,l] = sum_c W[o,c] Xt[b,l,c] + bias[o]
// EXACT round-2 core (measured 104 us on KV shape): BK=32, 16 KB LDS,
// global_load_lds(16B) into linear LDS, XOR chunk swizzle phys = q ^ ((r>>1)&3)
// (reads 2-way conflict-free), ds_read_b128 fragments, 16 MFMA / wave / K-step.
// Epilogues: EXPK (K rows: unnormalized exp(val+bias), NO reduction/atomics here —
// rowsum computed for free in ctx_kernel), QSMT (fused per-head softmax + transposed
// bf16 out), RESID (fp32 + resid out).
// grid: (64*MT, NB), XCD-aware swizzle (same nt => same XCD => shared L2 X panel).
template<int MT, bool RESID, bool PERB, bool QSMT, bool EXPK>
__global__ __launch_bounds__(256) void gemm_kernel(
    const unsigned short* __restrict__ Wb,   // [OC][512] bf16 (PERB: [B][512][512])
    const unsigned short* __restrict__ Xt,   // [B][L][512] bf16
    const float* __restrict__ bias,          // [OC]
    const float* __restrict__ resid,         // [B,512,L] float (RESID only)
    void* __restrict__ Yv)                   // bf16 or float
{
    const int bx = blockIdx.x;
    const int g  = bx >> 3;
    const int mt = g % MT;
    const int nt = (g / MT) * 8 + (bx & 7);
    const int b  = blockIdx.y;
    const int t  = threadIdx.x;
    const int wave = t >> 6, lane = t & 63;
    const int m0 = mt * 128, n0 = nt * 128;
    const int wm = (wave & 1) * 64, wn = (wave >> 1) * 64;
    const int OC = MT * 128;

    __shared__ alignas(16) unsigned short lA[128 * 32];
    __shared__ alignas(16) unsigned short lX[128 * 32];

    f32x4 acc[4][4] = {};

    const unsigned short* Wp = Wb + (PERB ? (size_t)b * NC * NC : 0);
    const unsigned short* Xb = Xt + (size_t)b * NL * NC;

    const int lr = lane & 15, q = lane >> 4;
    // fragment byte offsets; swizzle term constant across the 16-row unroll (16*4 % 8 == 0)
    const unsigned aoff = (unsigned)((wm + lr) * 64 + (q ^ (((wm + lr) >> 1) & 3)) * 16);
    const unsigned boff = (unsigned)((wn + lr) * 64 + (q ^ (((wn + lr) >> 1) & 3)) * 16);
    const int pb0 = wave * 128;   // this wave's chunk range [pb0, pb0+128)

    for (int k0 = 0; k0 < NC; k0 += 32) {
        #pragma unroll
        for (int cc = 0; cc < 2; ++cc) {
            const int pb = pb0 + cc * 64;      // wave-uniform LDS base chunk
            const int p  = pb + lane;          // this lane's chunk
            const int r  = p >> 2;
            const int qq = (p & 3) ^ ((r >> 1) & 3);
            gload16(Wp + (size_t)(m0 + r) * NC + k0 + qq * 8, &lA[pb * 8]);
            gload16(Xb + (size_t)(n0 + r) * NC + k0 + qq * 8, &lX[pb * 8]);
        }
        __syncthreads();

        bf16x8 af[4], bfx[4];
        #pragma unroll
        for (int i = 0; i < 4; ++i)
            af[i] = frag_from_u32x4(*(const u32x4*)((const char*)lA + aoff + i * 1024));
        #pragma unroll
        for (int j = 0; j < 4; ++j)
            bfx[j] = frag_from_u32x4(*(const u32x4*)((const char*)lX + boff + j * 1024));
        #pragma unroll
        for (int i = 0; i < 4; ++i)
            #pragma unroll
            for (int j = 0; j < 4; ++j)
                acc[i][j] = __builtin_amdgcn_mfma_f32_16x16x32_bf16(af[i], bfx[j], acc[i][j], 0, 0, 0);
        __syncthreads();
    }

    // epilogue: C/D layout col=lane&15, row=(lane>>4)*4+reg
    const int col = lane & 15, row0 = (lane >> 4) * 4;

    if constexpr (QSMT) {
        // fused per-head softmax over 64 output channels (= wave's 64 rows),
        // then TRANSPOSED bf16 write Y[b][l][o] (8B packed stores).
        #pragma unroll
        for (int i = 0; i < 4; ++i)
            #pragma unroll
            for (int r = 0; r < 4; ++r) {
                const float bo = bias[m0 + wm + i * 16 + row0 + r];
                #pragma unroll
                for (int j = 0; j < 4; ++j) acc[i][j][r] += bo;
            }
        float inv[4];
        #pragma unroll
        for (int j = 0; j < 4; ++j) {
            float m = -1e30f;
            #pragma unroll
            for (int i = 0; i < 4; ++i)
                #pragma unroll
                for (int r = 0; r < 4; ++r) m = fmaxf(m, acc[i][j][r]);
            m = fmaxf(m, __shfl_xor(m, 16));
            m = fmaxf(m, __shfl_xor(m, 32));
            float s = 0.f;
            #pragma unroll
            for (int i = 0; i < 4; ++i)
                #pragma unroll
                for (int r = 0; r < 4; ++r) {
                    const float e = __expf(acc[i][j][r] - m);
                    acc[i][j][r] = e;
                    s += e;
                }
            s += __shfl_xor(s, 16);
            s += __shfl_xor(s, 32);
            inv[j] = 1.0f / s;
        }
        unsigned short* Yq = (unsigned short*)Yv;
        #pragma unroll
        for (int j = 0; j < 4; ++j) {
            const size_t rowb = (size_t)b * NL * NC + (size_t)(n0 + wn + j * 16 + col) * NC;
            #pragma unroll
            for (int i = 0; i < 4; ++i) {
                const int o0 = m0 + wm + i * 16 + row0;
                unsigned lo = f2bf(acc[i][j][0] * inv[j]) | ((unsigned)f2bf(acc[i][j][1] * inv[j]) << 16);
                unsigned hi = f2bf(acc[i][j][2] * inv[j]) | ((unsigned)f2bf(acc[i][j][3] * inv[j]) << 16);
                *(unsigned long long*)(Yq + rowb + o0) =
                    (unsigned long long)lo | ((unsigned long long)hi << 32);
            }
        }
    } else if constexpr (EXPK) {
        // K rows (m0<NC): write UNNORMALIZED exp(val+bias). Normalization deferred:
        // rowsum comes from ctx_kernel's ones-MFMA; fold_kernel divides.
        unsigned short* Y = (unsigned short*)Yv;
        if (m0 < NC) {
            #pragma unroll
            for (int i = 0; i < 4; ++i)
                #pragma unroll
                for (int r = 0; r < 4; ++r) {
                    const int o = m0 + wm + i * 16 + row0 + r;
                    const float bo = bias[o];
                    const size_t rb = (size_t)b * OC * NL + (size_t)o * NL + n0 + wn;
                    #pragma unroll
                    for (int j = 0; j < 4; ++j)
                        Y[rb + j * 16 + col] = f2bf(__expf(acc[i][j][r] + bo));
                }
        } else {
            #pragma unroll
            for (int i = 0; i < 4; ++i)
                #pragma unroll
                for (int r = 0; r < 4; ++r) {
                    const int o = m0 + wm + i * 16 + row0 + r;
                    const float bo = bias[o];
                    const size_t rb = (size_t)b * OC * NL + (size_t)o * NL + n0 + wn;
                    #pragma unroll
                    for (int j = 0; j < 4; ++j)
                        Y[rb + j * 16 + col] = f2bf(acc[i][j][r] + bo);
                }
        }
    } else {
        #pragma unroll
        for (int i = 0; i < 4; ++i) {
            #pragma unroll
            for (int r = 0; r < 4; ++r) {
                const int o = m0 + wm + i * 16 + row0 + r;
                const float bo = bias[o];
                const size_t rb = (size_t)b * OC * NL + (size_t)o * NL + n0 + wn;
                if constexpr (RESID) {
                    float* Y = (float*)Yv;
                    #pragma unroll
                    for (int j = 0; j < 4; ++j) {
                        const size_t idx = rb + j * 16 + col;
                        Y[idx] = acc[i][j][r] + bo + resid[idx];
                    }
                } else {
                    unsigned short* Y = (unsigned short*)Yv;
                    #pragma unroll
                    for (int j = 0; j < 4; ++j)
                        Y[rb + j * 16 + col] = f2bf(acc[i][j][r] + bo);
                }
            }
        }
    }
}

// ctx[bh,k,v] = sum_l expK[b,h,k,l] * V[b,h,v,l]   grid (64, 16 L-splits), atomicAdd.
// Also computes rowsum[b,k] = sum_l expK[b,k,l] FOR FREE via a ones-column MFMA
// (B-operand = 1.0 => D[i][*] = row sum of A fragment accumulation).
__global__ __launch_bounds__(256) void ctx_kernel(
    const unsigned short* __restrict__ KV,   // [B][1024][L]: rows 0-511 exp(K), 512-1023 V
    float* __restrict__ ctx,                 // [64][64][64]
    float* __restrict__ rowsum)              // [B][512]
{
    const int bh = blockIdx.x;
    const int sp = blockIdx.y;
    const int t = threadIdx.x;
    const int wave = t >> 6, lane = t & 63;
    const int b = bh >> 3, h = bh & 7;
    const size_t base_k = ((size_t)b * 2 * NC + h * ND) * NL;
    const size_t base_v = base_k + (size_t)NC * NL;
    const int i = wave * 16 + (lane & 15);
    const int koff = (lane >> 4) * 8;
    const unsigned short* Ka = KV + base_k + (size_t)i * NL + koff;

    const u32x4 onesw = { 0x3f803f80u, 0x3f803f80u, 0x3f803f80u, 0x3f803f80u };
    const bf16x8 onef = frag_from_u32x4(onesw);

    f32x4 acc[4] = {};
    f32x4 accs = {};
    const int l0 = sp * (NL / 16);
    for (int l = l0; l < l0 + (NL / 16); l += 32) {
        bf16x8 a = ld_frag_g16(Ka + l);
        #pragma unroll
        for (int j = 0; j < 4; ++j) {
            bf16x8 bv = ld_frag_g16(KV + base_v + (size_t)(j * 16 + (lane & 15)) * NL + l + koff);
            acc[j] = __builtin_amdgcn_mfma_f32_16x16x32_bf16(a, bv, acc[j], 0, 0, 0);
        }
        accs = __builtin_amdgcn_mfma_f32_16x16x32_bf16(a, onef, accs, 0, 0, 0);
    }
    const int col = lane & 15, row0 = (lane >> 4) * 4;
    #pragma unroll
    for (int j = 0; j < 4; ++j)
        #pragma unroll
        for (int r = 0; r < 4; ++r)
            atomicAdd(&ctx[(size_t)bh * (ND * ND) + (size_t)(wave * 16 + row0 + r) * ND + j * 16 + col],
                      acc[j][r]);
    if (col == 0) {
        #pragma unroll
        for (int r = 0; r < 4; ++r)
            atomicAdd(&rowsum[(size_t)b * NC + h * ND + wave * 16 + row0 + r], accs[r]);
    }
}

// M_b[o, h*64+k] = sum_v Wr[o, h*64+v] * (ctx[b,h,k,v] / rowsum[b,h*64+k])
// grid 64 blocks (bh), 512 threads = 8 waves; wave covers 64 o-rows
__global__ __launch_bounds__(512) void fold_kernel(
    const unsigned short* __restrict__ Wrb,  // [512][512] bf16
    const float* __restrict__ ctxb,          // [64][64][64]
    const float* __restrict__ rowsum,        // [B][512]
    unsigned short* __restrict__ Mb)         // [B][512][512] bf16
{
    const int bh = blockIdx.x;
    const int b = bh >> 3, h = bh & 7;
    const int t = threadIdx.x;
    const int wave = t >> 6, lane = t & 63;

    __shared__ unsigned short lc[64 * 66];   // ctx bf16 [k][v], padded stride 66
    const float* cs = ctxb + (size_t)bh * (ND * ND);
    const float* rs = rowsum + (size_t)b * NC + h * ND;
    #pragma unroll
    for (int it = 0; it < 8; ++it) {
        int i = it * 512 + t;
        lc[(i >> 6) * 66 + (i & 63)] = f2bf(cs[i] / rs[i >> 6]);
    }
    __syncthreads();

    const int koff = (lane >> 4) * 8;
    f32x4 acc[4][4] = {};
    #pragma unroll
    for (int kk = 0; kk < 64; kk += 32) {
        bf16x8 af[4], bfx[4];
        #pragma unroll
        for (int i = 0; i < 4; ++i)
            af[i] = ld_frag_g16(Wrb + (size_t)(wave * 64 + i * 16 + (lane & 15)) * NC
                                + h * ND + kk + koff);
        #pragma unroll
        for (int j = 0; j < 4; ++j)
            bfx[j] = ld_frag_lds(&lc[(j * 16 + (lane & 15)) * 66 + kk + koff]);
        #pragma unroll
        for (int i = 0; i < 4; ++i)
            #pragma unroll
            for (int j = 0; j < 4; ++j)
                acc[i][j] = __builtin_amdgcn_mfma_f32_16x16x32_bf16(af[i], bfx[j], acc[i][j], 0, 0, 0);
    }

    const int col = lane & 15, row0 = (lane >> 4) * 4;
    #pragma unroll
    for (int i = 0; i < 4; ++i)
        #pragma unroll
        for (int r = 0; r < 4; ++r) {
            const int o = wave * 64 + i * 16 + row0 + r;
            #pragma unroll
            for (int j = 0; j < 4; ++j)
                Mb[(size_t)b * NC * NC + (size_t)o * NC + h * ND + j * 16 + col]
                    = f2bf(acc[i][j][r]);
        }
}

extern "C" void kernel_launch(void* const* d_in, const int* in_sizes, int n_in,
                              void* d_out, int out_size, void* d_ws, size_t ws_size,
                              hipStream_t stream) {
    (void)in_sizes; (void)n_in; (void)out_size; (void)ws_size;
    const float* input_   = (const float*)d_in[0];
    const float* context_ = (const float*)d_in[1];
    const float* Wk = (const float*)d_in[2];
    const float* bk = (const float*)d_in[3];
    const float* Wq = (const float*)d_in[4];
    const float* bq = (const float*)d_in[5];
    const float* Wv = (const float*)d_in[6];
    const float* bv = (const float*)d_in[7];
    const float* Wr = (const float*)d_in[8];
    const float* br = (const float*)d_in[9];
    float* out = (float*)d_out;

    // workspace layout (~204 MB):
    char* ws = (char*)d_ws;
    unsigned short* Wkvb = (unsigned short*)ws;                     // [1024][512] bf16 = 1 MB
    unsigned short* Wqb  = Wkvb + 2 * NC * NC;                      // 512 KB
    unsigned short* Wrb  = Wqb + NC * NC;                           // 512 KB
    float* bkv  = (float*)(Wrb + NC * NC);                          // 4 KB
    float* ctxb = bkv + 2 * NC;                                     // 1 MB
    float* rowsum = ctxb + NB * NH * ND * ND;                       // 16 KB (contiguous after ctxb)
    unsigned short* KVp = (unsigned short*)(rowsum + NB * NC);      // [B][1024][L] = 134 MB
    unsigned short* R2  = KVp + (size_t)NB * 2 * NC * NL;           // 67 MB: Xt_ctx, then Qp
    unsigned short* Mb  = KVp;                                      // reuse KVp after ctx/fold
    unsigned short* Xt_in = (unsigned short*)d_out;                 // scratch in out buffer (67 MB)

    // fused: transpose both inputs to bf16 [b][l][c] + prep (W cvt, bias concat,
    // zero ctx+rowsum) in one launch. z==2*NB section does prep grid-strided.
    transpose_prep_kernel<<<dim3(NL / 64, NC / 64, 2 * NB + 1), 256, 0, stream>>>(
        context_, input_, R2, Xt_in,
        Wk, Wv, Wq, Wr, bk, bv, Wkvb, bkv, ctxb);

    // K+V fused projection: [Wk;Wv] (1024x512) @ context -> KVp
    // K rows get unnormalized exp (deferred softmax)
    gemm_kernel<8, false, false, false, true><<<dim3(64 * 8, NB), 256, 0, stream>>>(
        Wkvb, R2, bkv, nullptr, KVp);

    // Q projection + fused per-head softmax, TRANSPOSED output Qp[b][l][c] -> R2
    gemm_kernel<4, false, false, true, false><<<dim3(64 * 4, NB), 256, 0, stream>>>(
        Wqb, Xt_in, bq, nullptr, R2);

    // ctx + free rowsum (ones-MFMA)
    ctx_kernel<<<dim3(NB * NH, 16), 256, 0, stream>>>(KVp, ctxb, rowsum);
    fold_kernel<<<NB * NH, 512, 0, stream>>>(Wrb, ctxb, rowsum, Mb);

    // out = M_b @ Qp^T + br + input   (X = Qp[b][l][c], W = Mb per-batch)
    gemm_kernel<4, true, true, false, false><<<dim3(64 * 4, NB), 256, 0, stream>>>(
        Mb, R2, br, input_, out);
}

// Round 5
// 621.825 us; speedup vs baseline: 1.1381x; 1.0856x over previous
//
#include <hip/hip_runtime.h>

#define NB 8
#define NC 512
#define NL 8192
#define NH 8
#define ND 64

typedef float f32x4 __attribute__((ext_vector_type(4)));
typedef __bf16 bf16x8 __attribute__((ext_vector_type(8)));
typedef unsigned int u32x4 __attribute__((ext_vector_type(4)));

__device__ __forceinline__ unsigned short f2bf(float f) {
    unsigned u = __builtin_bit_cast(unsigned, f);
    u += 0x7fffu + ((u >> 16) & 1u);
    return (unsigned short)(u >> 16);
}
__device__ __forceinline__ bf16x8 frag_from_u32x4(u32x4 v) {
    return __builtin_bit_cast(bf16x8, v);
}
// LDS fragment load with only-4B-aligned rows -> dword reads (fold kernel only)
__device__ __forceinline__ bf16x8 ld_frag_lds(const unsigned short* p) {
    const unsigned* q = (const unsigned*)p;
    u32x4 v = { q[0], q[1], q[2], q[3] };
    return frag_from_u32x4(v);
}
// Global fragment load: 16B aligned
__device__ __forceinline__ bf16x8 ld_frag_g16(const unsigned short* p) {
    return frag_from_u32x4(*(const u32x4*)p);
}
// LDS fragment load, 16B aligned, byte offset
__device__ __forceinline__ bf16x8 ldL(const unsigned short* Lb, unsigned off) {
    return frag_from_u32x4(*(const u32x4*)((const char*)Lb + off));
}

// async global->LDS, 16B per lane. dest = wave-uniform base + lane*16 (m104).
__device__ __forceinline__ void gload16(const unsigned short* g, unsigned short* l) {
    __builtin_amdgcn_global_load_lds(
        (const __attribute__((address_space(1))) unsigned int*)g,
        (__attribute__((address_space(3))) unsigned int*)l, 16, 0, 0);
}

// prep work item: W converts (Wk,Wv,Wq,Wr -> contiguous bf16), bias concat, zero ctx+rowsum
__device__ __forceinline__ void prep_body(int i,
    const float* __restrict__ Wk, const float* __restrict__ Wv,
    const float* __restrict__ Wq, const float* __restrict__ Wr,
    const float* __restrict__ bk, const float* __restrict__ bv,
    unsigned short* __restrict__ Wb, float* __restrict__ bkv, float* __restrict__ zf)
{
    const int WN = NC * NC;
    if (i < 4 * WN) {
        const float* src = (i < WN) ? Wk : (i < 2 * WN) ? Wv : (i < 3 * WN) ? Wq : Wr;
        Wb[i] = f2bf(src[i & (WN - 1)]);
    } else if (i < 4 * WN + 2 * NC) {
        int j = i - 4 * WN;
        bkv[j] = (j < NC) ? bk[j] : bv[j - NC];
    } else {
        zf[i - (4 * WN + 2 * NC)] = 0.f;
    }
}

// fp32 [b][c][l] -> bf16 [b][l][c], 64x64 tiles through LDS; PLUS fused prep section.
// grid.z = 2*NB+1: z<NB -> X0->Y0, z<2NB -> X1->Y1, z==2NB -> grid-strided prep.
__device__ __forceinline__ int ltidx(int c, int l) {
    return c * 64 + ((((l) >> 2) ^ ((c >> 2) & 15)) << 2) + (l & 3);
}
__global__ __launch_bounds__(256) void transpose_prep_kernel(
    const float* __restrict__ X0, const float* __restrict__ X1,
    unsigned short* __restrict__ Y0, unsigned short* __restrict__ Y1,
    const float* __restrict__ Wk, const float* __restrict__ Wv,
    const float* __restrict__ Wq, const float* __restrict__ Wr,
    const float* __restrict__ bk, const float* __restrict__ bv,
    unsigned short* __restrict__ Wb, float* __restrict__ bkv, float* __restrict__ zf)
{
    const int bz = blockIdx.z;
    const int t = threadIdx.x;
    if (bz == 2 * NB) {
        constexpr int total = 4 * NC * NC + 2 * NC + (NB * NH * ND * ND + NB * NC);
        const int stride = (NL / 64) * (NC / 64) * 256;
        for (int i = (blockIdx.y * (NL / 64) + blockIdx.x) * 256 + t; i < total; i += stride)
            prep_body(i, Wk, Wv, Wq, Wr, bk, bv, Wb, bkv, zf);
        return;
    }
    const float* X = (bz < NB) ? X0 : X1;
    unsigned short* Y = (bz < NB) ? Y0 : Y1;
    const int b = bz & (NB - 1);
    const int l0 = blockIdx.x * 64, c0 = blockIdx.y * 64;
    __shared__ alignas(16) unsigned short lt[64 * 64];
    const float* Xb = X + (size_t)b * NC * NL;
    #pragma unroll
    for (int it = 0; it < 4; ++it) {
        const int c = it * 16 + (t >> 4), l4 = (t & 15) * 4;
        f32x4 v = *(const f32x4*)(Xb + (size_t)(c0 + c) * NL + l0 + l4);
        unsigned lo = f2bf(v.x) | ((unsigned)f2bf(v.y) << 16);
        unsigned hi = f2bf(v.z) | ((unsigned)f2bf(v.w) << 16);
        unsigned* p = (unsigned*)&lt[ltidx(c, l4)];
        p[0] = lo; p[1] = hi;
    }
    __syncthreads();
    unsigned short* Yb = Y + (size_t)b * NL * NC;
    #pragma unroll
    for (int it = 0; it < 2; ++it) {
        const int l = it * 32 + (t >> 3), c8 = (t & 7) * 8;
        u32x4 o;
        #pragma unroll
        for (int d = 0; d < 4; ++d) {
            unsigned lo = lt[ltidx(c8 + 2 * d, l)];
            unsigned hi = lt[ltidx(c8 + 2 * d + 1, l)];
            o[d] = lo | (hi << 16);
        }
        *(u32x4*)(Yb + (size_t)(l0 + l) * NC + c0 + c8) = o;
    }
}

// stage one 128x64 bf16 half-tile (16 KB) into linear LDS via 2x global_load_lds,
// source pre-swizzled: logical chunk = phys ^ (row&7)  (T2; rule #21 involution)
__device__ __forceinline__ void stage_half(
    unsigned short* __restrict__ Ld, const unsigned short* __restrict__ Gs,
    int t, int wave)
{
    #pragma unroll
    for (int c = 0; c < 2; ++c) {
        const int idx = c * 512 + t;
        const int r = idx >> 3;
        const int ch = (idx & 7) ^ (r & 7);
        gload16(Gs + (size_t)r * NC + ch * 8, Ld + (size_t)(c * 512 + wave * 64) * 8);
    }
}

// ===== 8-phase 256x256 GEMM (m201 template port) =====
// BM=BN=256, BK=64, 8 waves (2M x 4N), 128 KB LDS (2 K-tile dbuf x {A,B} x 2 halves).
// Per K-tile: 4 phases, each {ds_read frags | stage 1 half of tile t+2 | SB;barrier;SB |
// setprio(1) 16 MFMA setprio(0) | [vmcnt(8) at P3] barrier}. B frags read once per tile
// (P0 = 12 ds_reads). Counted vmcnt: 8 loads in flight = tiles t+1,t+2 (T4).
// Epilogues: EXPK (KV, unnormalized exp on K rows), RESID (fp32 + resid).
template<int MT, bool RESID, bool PERB, bool EXPK>
__global__ __launch_bounds__(512) void gemm8_kernel(
    const unsigned short* __restrict__ Wb,   // [OC][512] bf16 (PERB: [B][512][512])
    const unsigned short* __restrict__ Xt,   // [B][L][512] bf16
    const float* __restrict__ bias,          // [OC]
    const float* __restrict__ resid,         // [B,512,L] float (RESID only)
    void* __restrict__ Yv)                   // bf16 or float
{
    const int bx = blockIdx.x;
    const int g  = bx >> 3;
    const int mt = g % MT;
    const int nt = (g / MT) * 8 + (bx & 7);  // XCD swizzle: same nt => same XCD
    const int b  = blockIdx.y;
    const int t  = threadIdx.x;
    const int wave = t >> 6, lane = t & 63;
    const int m0 = mt * 256, n0 = nt * 256;
    const int wm = wave >> 2, wn = wave & 3;   // 2M x 4N wave grid
    const int OC = MT * 256;

    __shared__ alignas(16) unsigned short L[65536];  // 128 KB

    f32x4 acc[8][4] = {};

    const unsigned short* Wp = Wb + (PERB ? (size_t)b * NC * NC : 0) + (size_t)m0 * NC;
    const unsigned short* Xp = Xt + (size_t)b * NL * NC + (size_t)n0 * NC;

    const int lr = lane & 15, qg = lane >> 4;
    const unsigned xr = (unsigned)(lr & 7);
    const unsigned cq0 = (((unsigned)qg) ^ xr) * 16u;        // kk=0 chunk byte off
    const unsigned cq1 = (((unsigned)qg + 4u) ^ xr) * 16u;   // kk=1
    const unsigned aB = (unsigned)(wm * 16384 + lr * 128);
    const unsigned bB = 32768u + (unsigned)((wn >> 1) * 16384 + ((wn & 1) * 64 + lr) * 128);

    // LDS elem offsets: A(par,half) = par*32768 + half*8192 ; B = +16384
    #define STA(par, half, kt) stage_half(&L[(par) * 32768 + (half) * 8192], \
        Wp + (size_t)((half) * 128) * NC + (kt) * 64, t, wave)
    #define STB(par, half, kt) stage_half(&L[(par) * 32768 + 16384 + (half) * 8192], \
        Xp + (size_t)((half) * 128) * NC + (kt) * 64, t, wave)

    // prologue: stage tiles 0,1 (16 loads/wave), wait tile0 (8 left = tile1)
    STA(0, 0, 0); STA(0, 1, 0); STB(0, 0, 0); STB(0, 1, 0);
    STA(1, 0, 1); STA(1, 1, 1); STB(1, 0, 1); STB(1, 1, 1);
    __builtin_amdgcn_sched_barrier(0);
    asm volatile("s_waitcnt vmcnt(8)" ::: "memory");
    __builtin_amdgcn_sched_barrier(0);
    __builtin_amdgcn_s_barrier();
    __builtin_amdgcn_sched_barrier(0);

    for (int kt = 0; kt < 8; ++kt) {
        const unsigned parB = (unsigned)((kt & 1) * 65536);
        const int par = kt & 1, ks = kt + 2;
        bf16x8 bf[4][2];
        #pragma unroll
        for (int q4 = 0; q4 < 4; ++q4) {
            // --- ds reads for this phase ---
            if (q4 == 0) {
                #pragma unroll
                for (int j = 0; j < 4; ++j) {
                    bf[j][0] = ldL(L, parB + bB + j * 2048 + cq0);
                    bf[j][1] = ldL(L, parB + bB + j * 2048 + cq1);
                }
            }
            bf16x8 af[2][2];
            #pragma unroll
            for (int di = 0; di < 2; ++di) {
                af[di][0] = ldL(L, parB + aB + (q4 * 2 + di) * 2048 + cq0);
                af[di][1] = ldL(L, parB + aB + (q4 * 2 + di) * 2048 + cq1);
            }
            // --- stage tile kt+2 (same parity; each half staged after its last reader) ---
            if (ks < 8) {
                if (q4 == 1)      { STB(par, 0, ks); }
                else if (q4 == 2) { STB(par, 1, ks); }
                else if (q4 == 3) { STA(par, 0, ks); STA(par, 1, ks); }
            }
            __builtin_amdgcn_sched_barrier(0);
            __builtin_amdgcn_s_barrier();
            __builtin_amdgcn_sched_barrier(0);
            __builtin_amdgcn_s_setprio(1);
            #pragma unroll
            for (int di = 0; di < 2; ++di)
                #pragma unroll
                for (int j = 0; j < 4; ++j) {
                    acc[q4 * 2 + di][j] = __builtin_amdgcn_mfma_f32_16x16x32_bf16(
                        af[di][0], bf[j][0], acc[q4 * 2 + di][j], 0, 0, 0);
                    acc[q4 * 2 + di][j] = __builtin_amdgcn_mfma_f32_16x16x32_bf16(
                        af[di][1], bf[j][1], acc[q4 * 2 + di][j], 0, 0, 0);
                }
            __builtin_amdgcn_s_setprio(0);
            __builtin_amdgcn_sched_barrier(0);
            if (q4 == 3) {
                if (kt < 6)       asm volatile("s_waitcnt vmcnt(8)" ::: "memory");
                else if (kt == 6) asm volatile("s_waitcnt vmcnt(0)" ::: "memory");
                __builtin_amdgcn_sched_barrier(0);
            }
            __builtin_amdgcn_s_barrier();
            __builtin_amdgcn_sched_barrier(0);
        }
    }
    #undef STA
    #undef STB

    // epilogue: C/D layout col=lane&15, row=(lane>>4)*4+reg
    const int col = lr, row0 = qg * 4;
    if constexpr (EXPK) {
        unsigned short* Y = (unsigned short*)Yv;
        const bool isK = (m0 < NC);
        #pragma unroll
        for (int i = 0; i < 8; ++i)
            #pragma unroll
            for (int r = 0; r < 4; ++r) {
                const int o = m0 + wm * 128 + i * 16 + row0 + r;
                const float bo = bias[o];
                const size_t rb = (size_t)b * OC * NL + (size_t)o * NL + n0 + wn * 64;
                #pragma unroll
                for (int j = 0; j < 4; ++j) {
                    float v = acc[i][j][r] + bo;
                    if (isK) v = __expf(v);
                    Y[rb + j * 16 + col] = f2bf(v);
                }
            }
    } else if constexpr (RESID) {
        float* Y = (float*)Yv;
        #pragma unroll
        for (int i = 0; i < 8; ++i)
            #pragma unroll
            for (int r = 0; r < 4; ++r) {
                const int o = m0 + wm * 128 + i * 16 + row0 + r;
                const float bo = bias[o];
                const size_t rb = (size_t)b * OC * NL + (size_t)o * NL + n0 + wn * 64;
                #pragma unroll
                for (int j = 0; j < 4; ++j) {
                    const size_t idx = rb + j * 16 + col;
                    Y[idx] = acc[i][j][r] + bo + resid[idx];
                }
            }
    } else {
        unsigned short* Y = (unsigned short*)Yv;
        #pragma unroll
        for (int i = 0; i < 8; ++i)
            #pragma unroll
            for (int r = 0; r < 4; ++r) {
                const int o = m0 + wm * 128 + i * 16 + row0 + r;
                const float bo = bias[o];
                const size_t rb = (size_t)b * OC * NL + (size_t)o * NL + n0 + wn * 64;
                #pragma unroll
                for (int j = 0; j < 4; ++j)
                    Y[rb + j * 16 + col] = f2bf(acc[i][j][r] + bo);
            }
    }
}

// ===== verified round-2 2-phase core: kept for the Q projection (QSMT epilogue) =====
template<int MT, bool RESID, bool PERB, bool QSMT, bool EXPK>
__global__ __launch_bounds__(256) void gemm_kernel(
    const unsigned short* __restrict__ Wb,
    const unsigned short* __restrict__ Xt,
    const float* __restrict__ bias,
    const float* __restrict__ resid,
    void* __restrict__ Yv)
{
    const int bx = blockIdx.x;
    const int g  = bx >> 3;
    const int mt = g % MT;
    const int nt = (g / MT) * 8 + (bx & 7);
    const int b  = blockIdx.y;
    const int t  = threadIdx.x;
    const int wave = t >> 6, lane = t & 63;
    const int m0 = mt * 128, n0 = nt * 128;
    const int wm = (wave & 1) * 64, wn = (wave >> 1) * 64;
    const int OC = MT * 128;

    __shared__ alignas(16) unsigned short lA[128 * 32];
    __shared__ alignas(16) unsigned short lX[128 * 32];

    f32x4 acc[4][4] = {};

    const unsigned short* Wp = Wb + (PERB ? (size_t)b * NC * NC : 0);
    const unsigned short* Xb = Xt + (size_t)b * NL * NC;

    const int lr = lane & 15, q = lane >> 4;
    const unsigned aoff = (unsigned)((wm + lr) * 64 + (q ^ (((wm + lr) >> 1) & 3)) * 16);
    const unsigned boff = (unsigned)((wn + lr) * 64 + (q ^ (((wn + lr) >> 1) & 3)) * 16);
    const int pb0 = wave * 128;

    for (int k0 = 0; k0 < NC; k0 += 32) {
        #pragma unroll
        for (int cc = 0; cc < 2; ++cc) {
            const int pb = pb0 + cc * 64;
            const int p  = pb + lane;
            const int r  = p >> 2;
            const int qq = (p & 3) ^ ((r >> 1) & 3);
            gload16(Wp + (size_t)(m0 + r) * NC + k0 + qq * 8, &lA[pb * 8]);
            gload16(Xb + (size_t)(n0 + r) * NC + k0 + qq * 8, &lX[pb * 8]);
        }
        __syncthreads();

        bf16x8 af[4], bfx[4];
        #pragma unroll
        for (int i = 0; i < 4; ++i)
            af[i] = frag_from_u32x4(*(const u32x4*)((const char*)lA + aoff + i * 1024));
        #pragma unroll
        for (int j = 0; j < 4; ++j)
            bfx[j] = frag_from_u32x4(*(const u32x4*)((const char*)lX + boff + j * 1024));
        #pragma unroll
        for (int i = 0; i < 4; ++i)
            #pragma unroll
            for (int j = 0; j < 4; ++j)
                acc[i][j] = __builtin_amdgcn_mfma_f32_16x16x32_bf16(af[i], bfx[j], acc[i][j], 0, 0, 0);
        __syncthreads();
    }

    const int col = lane & 15, row0 = (lane >> 4) * 4;

    if constexpr (QSMT) {
        #pragma unroll
        for (int i = 0; i < 4; ++i)
            #pragma unroll
            for (int r = 0; r < 4; ++r) {
                const float bo = bias[m0 + wm + i * 16 + row0 + r];
                #pragma unroll
                for (int j = 0; j < 4; ++j) acc[i][j][r] += bo;
            }
        float inv[4];
        #pragma unroll
        for (int j = 0; j < 4; ++j) {
            float m = -1e30f;
            #pragma unroll
            for (int i = 0; i < 4; ++i)
                #pragma unroll
                for (int r = 0; r < 4; ++r) m = fmaxf(m, acc[i][j][r]);
            m = fmaxf(m, __shfl_xor(m, 16));
            m = fmaxf(m, __shfl_xor(m, 32));
            float s = 0.f;
            #pragma unroll
            for (int i = 0; i < 4; ++i)
                #pragma unroll
                for (int r = 0; r < 4; ++r) {
                    const float e = __expf(acc[i][j][r] - m);
                    acc[i][j][r] = e;
                    s += e;
                }
            s += __shfl_xor(s, 16);
            s += __shfl_xor(s, 32);
            inv[j] = 1.0f / s;
        }
        unsigned short* Yq = (unsigned short*)Yv;
        #pragma unroll
        for (int j = 0; j < 4; ++j) {
            const size_t rowb = (size_t)b * NL * NC + (size_t)(n0 + wn + j * 16 + col) * NC;
            #pragma unroll
            for (int i = 0; i < 4; ++i) {
                const int o0 = m0 + wm + i * 16 + row0;
                unsigned lo = f2bf(acc[i][j][0] * inv[j]) | ((unsigned)f2bf(acc[i][j][1] * inv[j]) << 16);
                unsigned hi = f2bf(acc[i][j][2] * inv[j]) | ((unsigned)f2bf(acc[i][j][3] * inv[j]) << 16);
                *(unsigned long long*)(Yq + rowb + o0) =
                    (unsigned long long)lo | ((unsigned long long)hi << 32);
            }
        }
    } else if constexpr (EXPK) {
        unsigned short* Y = (unsigned short*)Yv;
        const bool isK = (m0 < NC);
        #pragma unroll
        for (int i = 0; i < 4; ++i)
            #pragma unroll
            for (int r = 0; r < 4; ++r) {
                const int o = m0 + wm + i * 16 + row0 + r;
                const float bo = bias[o];
                const size_t rb = (size_t)b * OC * NL + (size_t)o * NL + n0 + wn;
                #pragma unroll
                for (int j = 0; j < 4; ++j) {
                    float v = acc[i][j][r] + bo;
                    if (isK) v = __expf(v);
                    Y[rb + j * 16 + col] = f2bf(v);
                }
            }
    } else {
        #pragma unroll
        for (int i = 0; i < 4; ++i) {
            #pragma unroll
            for (int r = 0; r < 4; ++r) {
                const int o = m0 + wm + i * 16 + row0 + r;
                const float bo = bias[o];
                const size_t rb = (size_t)b * OC * NL + (size_t)o * NL + n0 + wn;
                if constexpr (RESID) {
                    float* Y = (float*)Yv;
                    #pragma unroll
                    for (int j = 0; j < 4; ++j) {
                        const size_t idx = rb + j * 16 + col;
                        Y[idx] = acc[i][j][r] + bo + resid[idx];
                    }
                } else {
                    unsigned short* Y = (unsigned short*)Yv;
                    #pragma unroll
                    for (int j = 0; j < 4; ++j)
                        Y[rb + j * 16 + col] = f2bf(acc[i][j][r] + bo);
                }
            }
        }
    }
}

// ctx[bh,k,v] = sum_l expK[b,h,k,l] * V[b,h,v,l]   grid (64, 16 L-splits), atomicAdd.
// rowsum[b,k] = sum_l expK for free via ones-column MFMA.
__global__ __launch_bounds__(256) void ctx_kernel(
    const unsigned short* __restrict__ KV,
    float* __restrict__ ctx,
    float* __restrict__ rowsum)
{
    const int bh = blockIdx.x;
    const int sp = blockIdx.y;
    const int t = threadIdx.x;
    const int wave = t >> 6, lane = t & 63;
    const int b = bh >> 3, h = bh & 7;
    const size_t base_k = ((size_t)b * 2 * NC + h * ND) * NL;
    const size_t base_v = base_k + (size_t)NC * NL;
    const int i = wave * 16 + (lane & 15);
    const int koff = (lane >> 4) * 8;
    const unsigned short* Ka = KV + base_k + (size_t)i * NL + koff;

    const u32x4 onesw = { 0x3f803f80u, 0x3f803f80u, 0x3f803f80u, 0x3f803f80u };
    const bf16x8 onef = frag_from_u32x4(onesw);

    f32x4 acc[4] = {};
    f32x4 accs = {};
    const int l0 = sp * (NL / 16);
    for (int l = l0; l < l0 + (NL / 16); l += 32) {
        bf16x8 a = ld_frag_g16(Ka + l);
        #pragma unroll
        for (int j = 0; j < 4; ++j) {
            bf16x8 bv = ld_frag_g16(KV + base_v + (size_t)(j * 16 + (lane & 15)) * NL + l + koff);
            acc[j] = __builtin_amdgcn_mfma_f32_16x16x32_bf16(a, bv, acc[j], 0, 0, 0);
        }
        accs = __builtin_amdgcn_mfma_f32_16x16x32_bf16(a, onef, accs, 0, 0, 0);
    }
    const int col = lane & 15, row0 = (lane >> 4) * 4;
    #pragma unroll
    for (int j = 0; j < 4; ++j)
        #pragma unroll
        for (int r = 0; r < 4; ++r)
            atomicAdd(&ctx[(size_t)bh * (ND * ND) + (size_t)(wave * 16 + row0 + r) * ND + j * 16 + col],
                      acc[j][r]);
    if (col == 0) {
        #pragma unroll
        for (int r = 0; r < 4; ++r)
            atomicAdd(&rowsum[(size_t)b * NC + h * ND + wave * 16 + row0 + r], accs[r]);
    }
}

// M_b[o, h*64+k] = sum_v Wr[o, h*64+v] * (ctx[b,h,k,v] / rowsum[b,h*64+k])
__global__ __launch_bounds__(512) void fold_kernel(
    const unsigned short* __restrict__ Wrb,
    const float* __restrict__ ctxb,
    const float* __restrict__ rowsum,
    unsigned short* __restrict__ Mb)
{
    const int bh = blockIdx.x;
    const int b = bh >> 3, h = bh & 7;
    const int t = threadIdx.x;
    const int wave = t >> 6, lane = t & 63;

    __shared__ unsigned short lc[64 * 66];
    const float* cs = ctxb + (size_t)bh * (ND * ND);
    const float* rs = rowsum + (size_t)b * NC + h * ND;
    #pragma unroll
    for (int it = 0; it < 8; ++it) {
        int i = it * 512 + t;
        lc[(i >> 6) * 66 + (i & 63)] = f2bf(cs[i] / rs[i >> 6]);
    }
    __syncthreads();

    const int koff = (lane >> 4) * 8;
    f32x4 acc[4][4] = {};
    #pragma unroll
    for (int kk = 0; kk < 64; kk += 32) {
        bf16x8 af[4], bfx[4];
        #pragma unroll
        for (int i = 0; i < 4; ++i)
            af[i] = ld_frag_g16(Wrb + (size_t)(wave * 64 + i * 16 + (lane & 15)) * NC
                                + h * ND + kk + koff);
        #pragma unroll
        for (int j = 0; j < 4; ++j)
            bfx[j] = ld_frag_lds(&lc[(j * 16 + (lane & 15)) * 66 + kk + koff]);
        #pragma unroll
        for (int i = 0; i < 4; ++i)
            #pragma unroll
            for (int j = 0; j < 4; ++j)
                acc[i][j] = __builtin_amdgcn_mfma_f32_16x16x32_bf16(af[i], bfx[j], acc[i][j], 0, 0, 0);
    }

    const int col = lane & 15, row0 = (lane >> 4) * 4;
    #pragma unroll
    for (int i = 0; i < 4; ++i)
        #pragma unroll
        for (int r = 0; r < 4; ++r) {
            const int o = wave * 64 + i * 16 + row0 + r;
            #pragma unroll
            for (int j = 0; j < 4; ++j)
                Mb[(size_t)b * NC * NC + (size_t)o * NC + h * ND + j * 16 + col]
                    = f2bf(acc[i][j][r]);
        }
}

extern "C" void kernel_launch(void* const* d_in, const int* in_sizes, int n_in,
                              void* d_out, int out_size, void* d_ws, size_t ws_size,
                              hipStream_t stream) {
    (void)in_sizes; (void)n_in; (void)out_size; (void)ws_size;
    const float* input_   = (const float*)d_in[0];
    const float* context_ = (const float*)d_in[1];
    const float* Wk = (const float*)d_in[2];
    const float* bk = (const float*)d_in[3];
    const float* Wq = (const float*)d_in[4];
    const float* bq = (const float*)d_in[5];
    const float* Wv = (const float*)d_in[6];
    const float* bv = (const float*)d_in[7];
    const float* Wr = (const float*)d_in[8];
    const float* br = (const float*)d_in[9];
    float* out = (float*)d_out;

    // workspace layout (~204 MB):
    char* ws = (char*)d_ws;
    unsigned short* Wkvb = (unsigned short*)ws;                     // [1024][512] bf16 = 1 MB
    unsigned short* Wqb  = Wkvb + 2 * NC * NC;                      // 512 KB
    unsigned short* Wrb  = Wqb + NC * NC;                           // 512 KB
    float* bkv  = (float*)(Wrb + NC * NC);                          // 4 KB
    float* ctxb = bkv + 2 * NC;                                     // 1 MB
    float* rowsum = ctxb + NB * NH * ND * ND;                       // 16 KB
    unsigned short* KVp = (unsigned short*)(rowsum + NB * NC);      // [B][1024][L] = 134 MB
    unsigned short* R2  = KVp + (size_t)NB * 2 * NC * NL;           // 67 MB: Xt_ctx, then Qp
    unsigned short* Mb  = KVp;                                      // reuse KVp after ctx/fold
    unsigned short* Xt_in = (unsigned short*)d_out;                 // scratch in out buffer

    // fused: transpose both inputs to bf16 [b][l][c] + prep (W cvt, bias concat, zeros)
    transpose_prep_kernel<<<dim3(NL / 64, NC / 64, 2 * NB + 1), 256, 0, stream>>>(
        context_, input_, R2, Xt_in,
        Wk, Wv, Wq, Wr, bk, bv, Wkvb, bkv, ctxb);

    // K+V fused projection (8-phase 256^2 core): K rows get unnormalized exp
    gemm8_kernel<4, false, false, true><<<dim3(128, NB), 512, 0, stream>>>(
        Wkvb, R2, bkv, nullptr, KVp);

    // Q projection + fused per-head softmax, transposed out (verified 2-phase core)
    gemm_kernel<4, false, false, true, false><<<dim3(256, NB), 256, 0, stream>>>(
        Wqb, Xt_in, bq, nullptr, R2);

    // ctx + free rowsum (ones-MFMA)
    ctx_kernel<<<dim3(NB * NH, 16), 256, 0, stream>>>(KVp, ctxb, rowsum);
    fold_kernel<<<NB * NH, 512, 0, stream>>>(Wrb, ctxb, rowsum, Mb);

    // out = M_b @ Qp^T + br + input  (8-phase core)
    gemm8_kernel<2, true, true, false><<<dim3(64, NB), 512, 0, stream>>>(
        Mb, R2, br, input_, out);
}

// Round 6
// 618.826 us; speedup vs baseline: 1.1436x; 1.0048x over previous
//
#include <hip/hip_runtime.h>

#define NB 8
#define NC 512
#define NL 8192
#define NH 8
#define ND 64

typedef float f32x4 __attribute__((ext_vector_type(4)));
typedef __bf16 bf16x8 __attribute__((ext_vector_type(8)));
typedef unsigned int u32x4 __attribute__((ext_vector_type(4)));

__device__ __forceinline__ unsigned short f2bf(float f) {
    unsigned u = __builtin_bit_cast(unsigned, f);
    u += 0x7fffu + ((u >> 16) & 1u);
    return (unsigned short)(u >> 16);
}
__device__ __forceinline__ bf16x8 frag_from_u32x4(u32x4 v) {
    return __builtin_bit_cast(bf16x8, v);
}
// LDS fragment load with only-4B-aligned rows -> dword reads (fold kernel only)
__device__ __forceinline__ bf16x8 ld_frag_lds(const unsigned short* p) {
    const unsigned* q = (const unsigned*)p;
    u32x4 v = { q[0], q[1], q[2], q[3] };
    return frag_from_u32x4(v);
}
// Global fragment load: 16B aligned
__device__ __forceinline__ bf16x8 ld_frag_g16(const unsigned short* p) {
    return frag_from_u32x4(*(const u32x4*)p);
}
// LDS fragment load, 16B aligned, byte offset
__device__ __forceinline__ bf16x8 ldL(const unsigned short* Lb, unsigned off) {
    return frag_from_u32x4(*(const u32x4*)((const char*)Lb + off));
}

// async global->LDS, 16B per lane. dest = wave-uniform base + lane*16 (m104).
__device__ __forceinline__ void gload16(const unsigned short* g, unsigned short* l) {
    __builtin_amdgcn_global_load_lds(
        (const __attribute__((address_space(1))) unsigned int*)g,
        (__attribute__((address_space(3))) unsigned int*)l, 16, 0, 0);
}

// prep work item: W converts (Wk,Wv,Wq,Wr -> contiguous bf16), bias concat, zero ctx+rowsum
__device__ __forceinline__ void prep_body(int i,
    const float* __restrict__ Wk, const float* __restrict__ Wv,
    const float* __restrict__ Wq, const float* __restrict__ Wr,
    const float* __restrict__ bk, const float* __restrict__ bv,
    unsigned short* __restrict__ Wb, float* __restrict__ bkv, float* __restrict__ zf)
{
    const int WN = NC * NC;
    if (i < 4 * WN) {
        const float* src = (i < WN) ? Wk : (i < 2 * WN) ? Wv : (i < 3 * WN) ? Wq : Wr;
        Wb[i] = f2bf(src[i & (WN - 1)]);
    } else if (i < 4 * WN + 2 * NC) {
        int j = i - 4 * WN;
        bkv[j] = (j < NC) ? bk[j] : bv[j - NC];
    } else {
        zf[i - (4 * WN + 2 * NC)] = 0.f;
    }
}

// fp32 [b][c][l] -> bf16 [b][l][c]. 64l x 256c tiles (32 KB LDS), 16-deep load ILP
// per thread, ~4096 blocks (4x fewer than before: less per-block launch/tail overhead).
// PLUS fused prep section (z == 2*NB).
__device__ __forceinline__ int ltidx(int c, int l) {
    return c * 64 + ((((l) >> 2) ^ ((c >> 2) & 15)) << 2) + (l & 3);
}
__global__ __launch_bounds__(256) void transpose_prep_kernel(
    const float* __restrict__ X0, const float* __restrict__ X1,
    unsigned short* __restrict__ Y0, unsigned short* __restrict__ Y1,
    const float* __restrict__ Wk, const float* __restrict__ Wv,
    const float* __restrict__ Wq, const float* __restrict__ Wr,
    const float* __restrict__ bk, const float* __restrict__ bv,
    unsigned short* __restrict__ Wb, float* __restrict__ bkv, float* __restrict__ zf)
{
    const int bz = blockIdx.z;
    const int t = threadIdx.x;
    if (bz == 2 * NB) {
        constexpr int total = 4 * NC * NC + 2 * NC + (NB * NH * ND * ND + NB * NC);
        const int stride = (NL / 64) * (NC / 256) * 256;
        for (int i = (blockIdx.y * (NL / 64) + blockIdx.x) * 256 + t; i < total; i += stride)
            prep_body(i, Wk, Wv, Wq, Wr, bk, bv, Wb, bkv, zf);
        return;
    }
    const float* X = (bz < NB) ? X0 : X1;
    unsigned short* Y = (bz < NB) ? Y0 : Y1;
    const int b = bz & (NB - 1);
    const int l0 = blockIdx.x * 64, c0 = blockIdx.y * 256;
    __shared__ alignas(16) unsigned short lt[256 * 64];   // 32 KB
    const float* Xb = X + (size_t)b * NC * NL;
    // phase 1: 16 independent f32x4 loads per thread (deep MLP for HBM latency)
    #pragma unroll
    for (int it = 0; it < 16; ++it) {
        const int c = it * 16 + (t >> 4), l4 = (t & 15) * 4;
        f32x4 v = *(const f32x4*)(Xb + (size_t)(c0 + c) * NL + l0 + l4);
        unsigned lo = f2bf(v.x) | ((unsigned)f2bf(v.y) << 16);
        unsigned hi = f2bf(v.z) | ((unsigned)f2bf(v.w) << 16);
        unsigned* p = (unsigned*)&lt[ltidx(c, l4)];
        p[0] = lo; p[1] = hi;
    }
    __syncthreads();
    // phase 2: 64 rows x 512 B contiguous writes
    unsigned short* Yb = Y + (size_t)b * NL * NC;
    #pragma unroll
    for (int it = 0; it < 8; ++it) {
        const int l = it * 8 + (t >> 5), c8 = (t & 31) * 8;
        u32x4 o;
        #pragma unroll
        for (int d = 0; d < 4; ++d) {
            unsigned lo = lt[ltidx(c8 + 2 * d, l)];
            unsigned hi = lt[ltidx(c8 + 2 * d + 1, l)];
            o[d] = lo | (hi << 16);
        }
        *(u32x4*)(Yb + (size_t)(l0 + l) * NC + c0 + c8) = o;
    }
}

// stage one 128x64 bf16 half-tile (16 KB) into linear LDS via 2x global_load_lds,
// source pre-swizzled: logical chunk = phys ^ (row&7)  (T2; rule #21 involution)
__device__ __forceinline__ void stage_half(
    unsigned short* __restrict__ Ld, const unsigned short* __restrict__ Gs,
    int t, int wave)
{
    #pragma unroll
    for (int c = 0; c < 2; ++c) {
        const int idx = c * 512 + t;
        const int r = idx >> 3;
        const int ch = (idx & 7) ^ (r & 7);
        gload16(Gs + (size_t)r * NC + ch * 8, Ld + (size_t)(c * 512 + wave * 64) * 8);
    }
}

// ===== 8-phase 256x256 GEMM (m201 template port) =====
// BM=BN=256, BK=64, 8 waves (2M x 4N), 128 KB LDS (2 K-tile dbuf x {A,B} x 2 halves).
// Per K-tile: 4 phases, each {ds_read frags | stage 1 half of tile t+2 | SB;barrier;SB |
// setprio(1) 16 MFMA setprio(0) | [vmcnt(8) at P3] barrier}. B frags read once per tile
// (P0 = 12 ds_reads). Counted vmcnt: 8 loads in flight = tiles t+1,t+2 (T4).
// Epilogues: EXPK (KV, unnormalized exp on K rows), RESID (fp32 + resid),
// QSMT (fused per-head q-softmax over 64 channels + transposed bf16 out).
template<int MT, bool RESID, bool PERB, bool EXPK, bool QSMT>
__global__ __launch_bounds__(512) void gemm8_kernel(
    const unsigned short* __restrict__ Wb,   // [OC][512] bf16 (PERB: [B][512][512])
    const unsigned short* __restrict__ Xt,   // [B][L][512] bf16
    const float* __restrict__ bias,          // [OC]
    const float* __restrict__ resid,         // [B,512,L] float (RESID only)
    void* __restrict__ Yv)                   // bf16 or float
{
    const int bx = blockIdx.x;
    const int g  = bx >> 3;
    const int mt = g % MT;
    const int nt = (g / MT) * 8 + (bx & 7);  // XCD swizzle: same nt => same XCD
    const int b  = blockIdx.y;
    const int t  = threadIdx.x;
    const int wave = t >> 6, lane = t & 63;
    const int m0 = mt * 256, n0 = nt * 256;
    const int wm = wave >> 2, wn = wave & 3;   // 2M x 4N wave grid
    const int OC = MT * 256;

    __shared__ alignas(16) unsigned short L[65536];  // 128 KB

    f32x4 acc[8][4] = {};

    const unsigned short* Wp = Wb + (PERB ? (size_t)b * NC * NC : 0) + (size_t)m0 * NC;
    const unsigned short* Xp = Xt + (size_t)b * NL * NC + (size_t)n0 * NC;

    const int lr = lane & 15, qg = lane >> 4;
    const unsigned xr = (unsigned)(lr & 7);
    const unsigned cq0 = (((unsigned)qg) ^ xr) * 16u;        // kk=0 chunk byte off
    const unsigned cq1 = (((unsigned)qg + 4u) ^ xr) * 16u;   // kk=1
    const unsigned aB = (unsigned)(wm * 16384 + lr * 128);
    const unsigned bB = 32768u + (unsigned)((wn >> 1) * 16384 + ((wn & 1) * 64 + lr) * 128);

    // LDS elem offsets: A(par,half) = par*32768 + half*8192 ; B = +16384
    #define STA(par, half, kt) stage_half(&L[(par) * 32768 + (half) * 8192], \
        Wp + (size_t)((half) * 128) * NC + (kt) * 64, t, wave)
    #define STB(par, half, kt) stage_half(&L[(par) * 32768 + 16384 + (half) * 8192], \
        Xp + (size_t)((half) * 128) * NC + (kt) * 64, t, wave)

    // prologue: stage tiles 0,1 (16 loads/wave), wait tile0 (8 left = tile1)
    STA(0, 0, 0); STA(0, 1, 0); STB(0, 0, 0); STB(0, 1, 0);
    STA(1, 0, 1); STA(1, 1, 1); STB(1, 0, 1); STB(1, 1, 1);
    __builtin_amdgcn_sched_barrier(0);
    asm volatile("s_waitcnt vmcnt(8)" ::: "memory");
    __builtin_amdgcn_sched_barrier(0);
    __builtin_amdgcn_s_barrier();
    __builtin_amdgcn_sched_barrier(0);

    for (int kt = 0; kt < 8; ++kt) {
        const unsigned parB = (unsigned)((kt & 1) * 65536);
        const int par = kt & 1, ks = kt + 2;
        bf16x8 bf[4][2];
        #pragma unroll
        for (int q4 = 0; q4 < 4; ++q4) {
            // --- ds reads for this phase ---
            if (q4 == 0) {
                #pragma unroll
                for (int j = 0; j < 4; ++j) {
                    bf[j][0] = ldL(L, parB + bB + j * 2048 + cq0);
                    bf[j][1] = ldL(L, parB + bB + j * 2048 + cq1);
                }
            }
            bf16x8 af[2][2];
            #pragma unroll
            for (int di = 0; di < 2; ++di) {
                af[di][0] = ldL(L, parB + aB + (q4 * 2 + di) * 2048 + cq0);
                af[di][1] = ldL(L, parB + aB + (q4 * 2 + di) * 2048 + cq1);
            }
            // --- stage tile kt+2 (same parity; each half staged after its last reader) ---
            if (ks < 8) {
                if (q4 == 1)      { STB(par, 0, ks); }
                else if (q4 == 2) { STB(par, 1, ks); }
                else if (q4 == 3) { STA(par, 0, ks); STA(par, 1, ks); }
            }
            __builtin_amdgcn_sched_barrier(0);
            __builtin_amdgcn_s_barrier();
            __builtin_amdgcn_sched_barrier(0);
            __builtin_amdgcn_s_setprio(1);
            #pragma unroll
            for (int di = 0; di < 2; ++di)
                #pragma unroll
                for (int j = 0; j < 4; ++j) {
                    acc[q4 * 2 + di][j] = __builtin_amdgcn_mfma_f32_16x16x32_bf16(
                        af[di][0], bf[j][0], acc[q4 * 2 + di][j], 0, 0, 0);
                    acc[q4 * 2 + di][j] = __builtin_amdgcn_mfma_f32_16x16x32_bf16(
                        af[di][1], bf[j][1], acc[q4 * 2 + di][j], 0, 0, 0);
                }
            __builtin_amdgcn_s_setprio(0);
            __builtin_amdgcn_sched_barrier(0);
            if (q4 == 3) {
                if (kt < 6)       asm volatile("s_waitcnt vmcnt(8)" ::: "memory");
                else if (kt == 6) asm volatile("s_waitcnt vmcnt(0)" ::: "memory");
                __builtin_amdgcn_sched_barrier(0);
            }
            __builtin_amdgcn_s_barrier();
            __builtin_amdgcn_sched_barrier(0);
        }
    }
    #undef STA
    #undef STB

    // epilogue: C/D layout col=lane&15, row=(lane>>4)*4+reg
    const int col = lr, row0 = qg * 4;
    if constexpr (QSMT) {
        // per-head softmax over 64 output channels. Wave covers 128 rows = 2 heads:
        // head hh = acc i-range [4hh, 4hh+4). Column j*16+col is held by the 4 qg-lanes
        // (16 acc values each) -> shfl_xor(16/32) completes the 64-row reduce.
        #pragma unroll
        for (int i = 0; i < 8; ++i)
            #pragma unroll
            for (int r = 0; r < 4; ++r) {
                const float bo = bias[m0 + wm * 128 + i * 16 + row0 + r];
                #pragma unroll
                for (int j = 0; j < 4; ++j) acc[i][j][r] += bo;
            }
        float inv[2][4];
        #pragma unroll
        for (int hh = 0; hh < 2; ++hh)
            #pragma unroll
            for (int j = 0; j < 4; ++j) {
                float m = -1e30f;
                #pragma unroll
                for (int i = 0; i < 4; ++i)
                    #pragma unroll
                    for (int r = 0; r < 4; ++r) m = fmaxf(m, acc[hh * 4 + i][j][r]);
                m = fmaxf(m, __shfl_xor(m, 16));
                m = fmaxf(m, __shfl_xor(m, 32));
                float s = 0.f;
                #pragma unroll
                for (int i = 0; i < 4; ++i)
                    #pragma unroll
                    for (int r = 0; r < 4; ++r) {
                        const float e = __expf(acc[hh * 4 + i][j][r] - m);
                        acc[hh * 4 + i][j][r] = e;
                        s += e;
                    }
                s += __shfl_xor(s, 16);
                s += __shfl_xor(s, 32);
                inv[hh][j] = 1.0f / s;
            }
        // TRANSPOSED bf16 write Y[b][l][o], 8B packed stores
        unsigned short* Yq = (unsigned short*)Yv;
        #pragma unroll
        for (int j = 0; j < 4; ++j) {
            const size_t rowb = (size_t)b * NL * NC + (size_t)(n0 + wn * 64 + j * 16 + col) * NC;
            #pragma unroll
            for (int i = 0; i < 8; ++i) {
                const float iv = inv[i >> 2][j];
                const int o0 = m0 + wm * 128 + i * 16 + row0;
                unsigned lo = f2bf(acc[i][j][0] * iv) | ((unsigned)f2bf(acc[i][j][1] * iv) << 16);
                unsigned hi = f2bf(acc[i][j][2] * iv) | ((unsigned)f2bf(acc[i][j][3] * iv) << 16);
                *(unsigned long long*)(Yq + rowb + o0) =
                    (unsigned long long)lo | ((unsigned long long)hi << 32);
            }
        }
    } else if constexpr (EXPK) {
        unsigned short* Y = (unsigned short*)Yv;
        const bool isK = (m0 < NC);
        #pragma unroll
        for (int i = 0; i < 8; ++i)
            #pragma unroll
            for (int r = 0; r < 4; ++r) {
                const int o = m0 + wm * 128 + i * 16 + row0 + r;
                const float bo = bias[o];
                const size_t rb = (size_t)b * OC * NL + (size_t)o * NL + n0 + wn * 64;
                #pragma unroll
                for (int j = 0; j < 4; ++j) {
                    float v = acc[i][j][r] + bo;
                    if (isK) v = __expf(v);
                    Y[rb + j * 16 + col] = f2bf(v);
                }
            }
    } else if constexpr (RESID) {
        float* Y = (float*)Yv;
        #pragma unroll
        for (int i = 0; i < 8; ++i)
            #pragma unroll
            for (int r = 0; r < 4; ++r) {
                const int o = m0 + wm * 128 + i * 16 + row0 + r;
                const float bo = bias[o];
                const size_t rb = (size_t)b * OC * NL + (size_t)o * NL + n0 + wn * 64;
                #pragma unroll
                for (int j = 0; j < 4; ++j) {
                    const size_t idx = rb + j * 16 + col;
                    Y[idx] = acc[i][j][r] + bo + resid[idx];
                }
            }
    } else {
        unsigned short* Y = (unsigned short*)Yv;
        #pragma unroll
        for (int i = 0; i < 8; ++i)
            #pragma unroll
            for (int r = 0; r < 4; ++r) {
                const int o = m0 + wm * 128 + i * 16 + row0 + r;
                const float bo = bias[o];
                const size_t rb = (size_t)b * OC * NL + (size_t)o * NL + n0 + wn * 64;
                #pragma unroll
                for (int j = 0; j < 4; ++j)
                    Y[rb + j * 16 + col] = f2bf(acc[i][j][r] + bo);
            }
    }
}

// ctx[bh,k,v] = sum_l expK[b,h,k,l] * V[b,h,v,l]   grid (64, 16 L-splits), atomicAdd.
// rowsum[b,k] = sum_l expK for free via ones-column MFMA.
__global__ __launch_bounds__(256) void ctx_kernel(
    const unsigned short* __restrict__ KV,
    float* __restrict__ ctx,
    float* __restrict__ rowsum)
{
    const int bh = blockIdx.x;
    const int sp = blockIdx.y;
    const int t = threadIdx.x;
    const int wave = t >> 6, lane = t & 63;
    const int b = bh >> 3, h = bh & 7;
    const size_t base_k = ((size_t)b * 2 * NC + h * ND) * NL;
    const size_t base_v = base_k + (size_t)NC * NL;
    const int i = wave * 16 + (lane & 15);
    const int koff = (lane >> 4) * 8;
    const unsigned short* Ka = KV + base_k + (size_t)i * NL + koff;

    const u32x4 onesw = { 0x3f803f80u, 0x3f803f80u, 0x3f803f80u, 0x3f803f80u };
    const bf16x8 onef = frag_from_u32x4(onesw);

    f32x4 acc[4] = {};
    f32x4 accs = {};
    const int l0 = sp * (NL / 16);
    for (int l = l0; l < l0 + (NL / 16); l += 32) {
        bf16x8 a = ld_frag_g16(Ka + l);
        #pragma unroll
        for (int j = 0; j < 4; ++j) {
            bf16x8 bv = ld_frag_g16(KV + base_v + (size_t)(j * 16 + (lane & 15)) * NL + l + koff);
            acc[j] = __builtin_amdgcn_mfma_f32_16x16x32_bf16(a, bv, acc[j], 0, 0, 0);
        }
        accs = __builtin_amdgcn_mfma_f32_16x16x32_bf16(a, onef, accs, 0, 0, 0);
    }
    const int col = lane & 15, row0 = (lane >> 4) * 4;
    #pragma unroll
    for (int j = 0; j < 4; ++j)
        #pragma unroll
        for (int r = 0; r < 4; ++r)
            atomicAdd(&ctx[(size_t)bh * (ND * ND) + (size_t)(wave * 16 + row0 + r) * ND + j * 16 + col],
                      acc[j][r]);
    if (col == 0) {
        #pragma unroll
        for (int r = 0; r < 4; ++r)
            atomicAdd(&rowsum[(size_t)b * NC + h * ND + wave * 16 + row0 + r], accs[r]);
    }
}

// M_b[o, h*64+k] = sum_v Wr[o, h*64+v] * (ctx[b,h,k,v] / rowsum[b,h*64+k])
__global__ __launch_bounds__(512) void fold_kernel(
    const unsigned short* __restrict__ Wrb,
    const float* __restrict__ ctxb,
    const float* __restrict__ rowsum,
    unsigned short* __restrict__ Mb)
{
    const int bh = blockIdx.x;
    const int b = bh >> 3, h = bh & 7;
    const int t = threadIdx.x;
    const int wave = t >> 6, lane = t & 63;

    __shared__ unsigned short lc[64 * 66];
    const float* cs = ctxb + (size_t)bh * (ND * ND);
    const float* rs = rowsum + (size_t)b * NC + h * ND;
    #pragma unroll
    for (int it = 0; it < 8; ++it) {
        int i = it * 512 + t;
        lc[(i >> 6) * 66 + (i & 63)] = f2bf(cs[i] / rs[i >> 6]);
    }
    __syncthreads();

    const int koff = (lane >> 4) * 8;
    f32x4 acc[4][4] = {};
    #pragma unroll
    for (int kk = 0; kk < 64; kk += 32) {
        bf16x8 af[4], bfx[4];
        #pragma unroll
        for (int i = 0; i < 4; ++i)
            af[i] = ld_frag_g16(Wrb + (size_t)(wave * 64 + i * 16 + (lane & 15)) * NC
                                + h * ND + kk + koff);
        #pragma unroll
        for (int j = 0; j < 4; ++j)
            bfx[j] = ld_frag_lds(&lc[(j * 16 + (lane & 15)) * 66 + kk + koff]);
        #pragma unroll
        for (int i = 0; i < 4; ++i)
            #pragma unroll
            for (int j = 0; j < 4; ++j)
                acc[i][j] = __builtin_amdgcn_mfma_f32_16x16x32_bf16(af[i], bfx[j], acc[i][j], 0, 0, 0);
    }

    const int col = lane & 15, row0 = (lane >> 4) * 4;
    #pragma unroll
    for (int i = 0; i < 4; ++i)
        #pragma unroll
        for (int r = 0; r < 4; ++r) {
            const int o = wave * 64 + i * 16 + row0 + r;
            #pragma unroll
            for (int j = 0; j < 4; ++j)
                Mb[(size_t)b * NC * NC + (size_t)o * NC + h * ND + j * 16 + col]
                    = f2bf(acc[i][j][r]);
        }
}

extern "C" void kernel_launch(void* const* d_in, const int* in_sizes, int n_in,
                              void* d_out, int out_size, void* d_ws, size_t ws_size,
                              hipStream_t stream) {
    (void)in_sizes; (void)n_in; (void)out_size; (void)ws_size;
    const float* input_   = (const float*)d_in[0];
    const float* context_ = (const float*)d_in[1];
    const float* Wk = (const float*)d_in[2];
    const float* bk = (const float*)d_in[3];
    const float* Wq = (const float*)d_in[4];
    const float* bq = (const float*)d_in[5];
    const float* Wv = (const float*)d_in[6];
    const float* bv = (const float*)d_in[7];
    const float* Wr = (const float*)d_in[8];
    const float* br = (const float*)d_in[9];
    float* out = (float*)d_out;

    // workspace layout (~204 MB):
    char* ws = (char*)d_ws;
    unsigned short* Wkvb = (unsigned short*)ws;                     // [1024][512] bf16 = 1 MB
    unsigned short* Wqb  = Wkvb + 2 * NC * NC;                      // 512 KB
    unsigned short* Wrb  = Wqb + NC * NC;                           // 512 KB
    float* bkv  = (float*)(Wrb + NC * NC);                          // 4 KB
    float* ctxb = bkv + 2 * NC;                                     // 1 MB
    float* rowsum = ctxb + NB * NH * ND * ND;                       // 16 KB
    unsigned short* KVp = (unsigned short*)(rowsum + NB * NC);      // [B][1024][L] = 134 MB
    unsigned short* R2  = KVp + (size_t)NB * 2 * NC * NL;           // 67 MB: Xt_ctx, then Qp
    unsigned short* Mb  = KVp;                                      // reuse KVp after ctx/fold
    unsigned short* Xt_in = (unsigned short*)d_out;                 // scratch in out buffer

    // fused: transpose both inputs to bf16 [b][l][c] + prep (W cvt, bias concat, zeros)
    transpose_prep_kernel<<<dim3(NL / 64, NC / 256, 2 * NB + 1), 256, 0, stream>>>(
        context_, input_, R2, Xt_in,
        Wk, Wv, Wq, Wr, bk, bv, Wkvb, bkv, ctxb);

    // K+V fused projection (8-phase 256^2 core): K rows get unnormalized exp
    gemm8_kernel<4, false, false, true, false><<<dim3(128, NB), 512, 0, stream>>>(
        Wkvb, R2, bkv, nullptr, KVp);

    // Q projection + fused per-head softmax, transposed out (8-phase core now)
    gemm8_kernel<2, false, false, false, true><<<dim3(64, NB), 512, 0, stream>>>(
        Wqb, Xt_in, bq, nullptr, R2);

    // ctx + free rowsum (ones-MFMA)
    ctx_kernel<<<dim3(NB * NH, 16), 256, 0, stream>>>(KVp, ctxb, rowsum);
    fold_kernel<<<NB * NH, 512, 0, stream>>>(Wrb, ctxb, rowsum, Mb);

    // out = M_b @ Qp^T + br + input  (8-phase core)
    gemm8_kernel<2, true, true, false, false><<<dim3(64, NB), 512, 0, stream>>>(
        Mb, R2, br, input_, out);
}